// Round 11
// baseline (1981.027 us; speedup 1.0000x reference)
//
#include <hip/hip_runtime.h>

// Seq2seq LSTM: 2-layer encoder (S=128) + attention decoder (T=64), B=64, H=1024, V=32000.
// v9: chain kept at v8 (structural floor ~7.5us/step). NEW: 256x256 8-wave quadrant-phased
// MFMA GEMM (T2 swizzle + phase barriers + setprio + XCD swizzle) for the logits GEMM and
// both x@Wx precompute GEMMs; attention reads block-major slabs directly (reshape deleted).

#define Bv 64
#define Sv 128
#define Tv 64
#define Hv 1024
#define H4v 4096
#define Vv 32000
#define NBLK 256

using bf16x8 = __attribute__((ext_vector_type(8))) short;
using f32x4  = __attribute__((ext_vector_type(4))) float;

typedef __attribute__((address_space(1))) const void gvoid_t;
typedef __attribute__((address_space(3))) void lvoid_t;

__device__ __forceinline__ void gload16(const void* g, void* l) {
  __builtin_amdgcn_global_load_lds((gvoid_t*)g, (lvoid_t*)l, 16, 0, 0);
}

__device__ __forceinline__ float bf2f(unsigned short u) {
  unsigned int v = ((unsigned int)u) << 16;
  return __uint_as_float(v);
}
__device__ __forceinline__ unsigned short f2bf(float f) {
  unsigned int u = __float_as_uint(f);
  return (unsigned short)((u + 0x7FFFu + ((u >> 16) & 1u)) >> 16);
}
__device__ __forceinline__ float sigm(float x) { return 1.f / (1.f + __expf(-x)); }
__device__ __forceinline__ float tanh_f(float x) {
  float ax = fabsf(x);
  float e = __expf(-2.f * ax);
  float t = (1.f - e) / (1.f + e);
  return copysignf(t, x);
}

__device__ __forceinline__ int4 ldx4(const unsigned short* p) {
  int4 r;
  asm volatile("global_load_dwordx4 %0, %1, off" : "=v"(r) : "v"(p));
  return r;
}
__device__ __forceinline__ int2 ldx2(const unsigned short* p) {
  int2 r;
  asm volatile("global_load_dwordx2 %0, %1, off" : "=v"(r) : "v"(p));
  return r;
}
__device__ __forceinline__ void stx2u_wt(unsigned short* p, int2 v) {
  asm volatile("global_store_dwordx2 %0, %1, off sc0 sc1" :: "v"(p), "v"(v) : "memory");
}
__device__ __forceinline__ void vm_wait_c(int n) {
  switch (n) {
    case 28: asm volatile("s_waitcnt vmcnt(28)" ::: "memory"); break;
    case 24: asm volatile("s_waitcnt vmcnt(24)" ::: "memory"); break;
    case 20: asm volatile("s_waitcnt vmcnt(20)" ::: "memory"); break;
    case 16: asm volatile("s_waitcnt vmcnt(16)" ::: "memory"); break;
    case 12: asm volatile("s_waitcnt vmcnt(12)" ::: "memory"); break;
    case 8:  asm volatile("s_waitcnt vmcnt(8)"  ::: "memory"); break;
    case 4:  asm volatile("s_waitcnt vmcnt(4)"  ::: "memory"); break;
    default: asm volatile("s_waitcnt vmcnt(0)"  ::: "memory"); break;
  }
}

// ---- RMW-free flag sync ----
__device__ __forceinline__ void wait_all64(int* f, int tid) {
  if (tid < 64) {
    int it = 0;
    while (true) {
      int v = __hip_atomic_load(f + tid, __ATOMIC_RELAXED, __HIP_MEMORY_SCOPE_AGENT);
      if (__all(v != 0)) break;
      __builtin_amdgcn_s_sleep(2);
      if (++it > (1 << 17)) break;
    }
  }
  __syncthreads();
}
__device__ __forceinline__ void wait_all128(int* f, int tid) {
  if (tid < 64) {
    int it = 0;
    while (true) {
      int a = __hip_atomic_load(f + tid, __ATOMIC_RELAXED, __HIP_MEMORY_SCOPE_AGENT);
      int b = __hip_atomic_load(f + tid + 64, __ATOMIC_RELAXED, __HIP_MEMORY_SCOPE_AGENT);
      if (__all((a != 0) && (b != 0))) break;
      __builtin_amdgcn_s_sleep(2);
      if (++it > (1 << 17)) break;
    }
  }
  __syncthreads();
}
__device__ __forceinline__ void post_flag(int* f, int tid) {
  __syncthreads();
  if (tid == 0) __hip_atomic_store(f, 1, __ATOMIC_RELAXED, __HIP_MEMORY_SCOPE_AGENT);
}

// ---------------- transpose + fp32->bf16 convert ----------------
__global__ __launch_bounds__(256) void transpose_bf16(const float* __restrict__ in,
                                                      unsigned short* __restrict__ out,
                                                      int R, int C, int ostride) {
  __shared__ float tile[32][33];
  int tx = threadIdx.x, ty = threadIdx.y;
  int c0 = blockIdx.x * 32, r0 = blockIdx.y * 32;
#pragma unroll
  for (int i = 0; i < 32; i += 8)
    tile[ty + i][tx] = in[(size_t)(r0 + ty + i) * C + c0 + tx];
  __syncthreads();
#pragma unroll
  for (int i = 0; i < 32; i += 8)
    out[(size_t)(c0 + ty + i) * ostride + r0 + tx] = f2bf(tile[tx][ty + i]);
}

// ---------------- embedding gather ----------------
__global__ __launch_bounds__(256) void gather_emb(const int* __restrict__ toks,
                                                  const float* __restrict__ emb,
                                                  unsigned short* __restrict__ dst) {
  int r = blockIdx.x, tid = threadIdx.x;
  int tok = toks[r];
  int j = tid * 4;
  float4 v = *(const float4*)&emb[(size_t)tok * Hv + j];
  ushort4 o;
  o.x = f2bf(v.x); o.y = f2bf(v.y); o.z = f2bf(v.z); o.w = f2bf(v.w);
  *(ushort4*)&dst[(size_t)r * Hv + j] = o;
}

// ---------------- init ----------------
__global__ __launch_bounds__(256) void init_k(unsigned short* __restrict__ zhx,
                                              unsigned short* __restrict__ hdx0,
                                              const float* __restrict__ h0,
                                              int* __restrict__ flg) {
  int idx = blockIdx.x * 256 + threadIdx.x;
  int j = idx & (Hv - 1);
  int b = idx >> 10;
  zhx[idx] = 0;
  hdx0[(j >> 4) * 1024 + b * 16 + (j & 15)] = f2bf(h0[j]);
  if (idx < 28672) flg[idx] = 0;
}

// ---------------- 128x128 MFMA GEMM (kept for CAT: EPI 2 = tanh->bf16 +bias) ----------------
__global__ __launch_bounds__(256) void gemm128_tanh(const unsigned short* __restrict__ A,
                                                    const unsigned short* __restrict__ Bt,
                                                    const float* __restrict__ bias,
                                                    unsigned short* __restrict__ Cbf,
                                                    int M, int N, int K) {
  __shared__ unsigned short As[128 * 64];
  __shared__ unsigned short Bs[128 * 64];
  int tid = threadIdx.x, lane = tid & 63, w = tid >> 6;
  int wr = w >> 1, wc = w & 1;
  int m0 = blockIdx.y * 128, n0 = blockIdx.x * 128;
  f32x4 acc[4][4] = {};
  for (int k0 = 0; k0 < K; k0 += 64) {
    __syncthreads();
#pragma unroll
    for (int q = 0; q < 4; ++q) {
      int idx = q * 256 + tid;
      int row = idx >> 3, phys = idx & 7, lg = phys ^ (row & 7);
      gload16(A + (size_t)(m0 + row) * K + k0 + lg * 8, &As[idx * 8]);
    }
#pragma unroll
    for (int q = 0; q < 4; ++q) {
      int idx = q * 256 + tid;
      int row = idx >> 3, phys = idx & 7, lg = phys ^ (row & 7);
      gload16(Bt + (size_t)(n0 + row) * K + k0 + lg * 8, &Bs[idx * 8]);
    }
    __syncthreads();
#pragma unroll
    for (int kk = 0; kk < 64; kk += 32) {
      int lgb = (kk >> 3) + (lane >> 4);
      bf16x8 af[4], bfr[4];
#pragma unroll
      for (int m = 0; m < 4; ++m) {
        int row = wr * 64 + m * 16 + (lane & 15);
        af[m] = *(const bf16x8*)&As[(row * 8 + (lgb ^ (row & 7))) * 8];
      }
#pragma unroll
      for (int n = 0; n < 4; ++n) {
        int row = wc * 64 + n * 16 + (lane & 15);
        bfr[n] = *(const bf16x8*)&Bs[(row * 8 + (lgb ^ (row & 7))) * 8];
      }
#pragma unroll
      for (int m = 0; m < 4; ++m)
#pragma unroll
        for (int n = 0; n < 4; ++n)
          acc[m][n] = __builtin_amdgcn_mfma_f32_16x16x32_bf16(af[m], bfr[n], acc[m][n], 0, 0, 0);
    }
  }
#pragma unroll
  for (int m = 0; m < 4; ++m)
#pragma unroll
    for (int n = 0; n < 4; ++n) {
      int col = n0 + wc * 64 + n * 16 + (lane & 15);
      float bv = bias[col];
#pragma unroll
      for (int j = 0; j < 4; ++j) {
        int row = m0 + wr * 64 + m * 16 + (lane >> 4) * 4 + j;
        Cbf[(size_t)row * N + col] = f2bf(tanhf(acc[m][n][j] + bv));
      }
    }
}

// ---------------- 256x256 8-wave quadrant-phased MFMA GEMM ----------------
// EPI: 3 = fused logits (exp-sum partials + tgt gather), 4/5 = chain-layout XPRE (+bias).
// 512 threads = 8 waves (2 wm x 4 wn); per wave output 128x64; K-tile 64, double-buffered
// LDS (2x64KB), XOR-granule swizzle (conflict-free b128), per-quadrant barrier phases,
// setprio around MFMA, XCD-swizzled blockIdx (nwg % 8 == 0 required).
template <int EPI>
__global__ __launch_bounds__(512, 2) void gemm256(const unsigned short* __restrict__ A,
                                                  const unsigned short* __restrict__ Bt,
                                                  const float* __restrict__ bias,
                                                  unsigned short* __restrict__ Cbf,
                                                  int M, int N, int K, int MT,
                                                  float* __restrict__ partial,
                                                  float* __restrict__ tlog,
                                                  const int* __restrict__ tgt) {
  __shared__ unsigned short LB[2][32768];  // per buffer: A[256][64] @0, B[256][64] @16384
  const int tid = threadIdx.x, lane = tid & 63, w = tid >> 6;
  const int wm = w >> 2, wn = w & 3;
  const int l15 = lane & 15, hi = lane >> 4;
  // XCD-aware bijective swizzle (nwg % 8 == 0)
  int nwg = gridDim.x;
  int swz = (blockIdx.x & 7) * (nwg >> 3) + (blockIdx.x >> 3);
  const int m0 = (swz % MT) * 256;
  const int n0 = (swz / MT) * 256;
  const int NKT = K >> 6;

  // stage half h (0,1 = A halves; 2,3 = B halves) of K-tile kt into buffer kt&1
  auto stage_half = [&](int kt, int h) {
    int bsel = kt & 1;
    int k0 = kt * 64;
#pragma unroll
    for (int rep = 0; rep < 2; ++rep) {
      int pg = (h & 1) * 1024 + rep * 512 + tid;  // granule within region
      int row = pg >> 3, pk = pg & 7, kg = pk ^ (row & 7);
      if (h < 2)
        gload16(A + (size_t)(m0 + row) * K + k0 + kg * 8, &LB[bsel][pg * 8]);
      else
        gload16(Bt + (size_t)(n0 + row) * K + k0 + kg * 8, &LB[bsel][16384 + pg * 8]);
    }
  };

  // prologue: stage K-tile 0 fully
#pragma unroll
  for (int h = 0; h < 4; ++h) stage_half(0, h);
  asm volatile("s_waitcnt vmcnt(0)" ::: "memory");
  __syncthreads();

  f32x4 acc[8][4] = {};
  const int ar7 = l15 & 7;  // row&7 for all fragment rows (row = ...*16 + l15)
  for (int kt = 0; kt < NKT; ++kt) {
    const unsigned short* buf = LB[kt & 1];
#pragma unroll
    for (int q = 0; q < 4; ++q) {
      const int mq = q & 1, nq = q >> 1;
      bf16x8 af[4][2], bf[2][2];
#pragma unroll
      for (int mf = 0; mf < 4; ++mf) {
        int row = wm * 128 + (mq * 4 + mf) * 16 + l15;
#pragma unroll
        for (int ks = 0; ks < 2; ++ks)
          af[mf][ks] = *(const bf16x8*)&buf[(row * 8 + ((ks * 4 + hi) ^ ar7)) * 8];
      }
#pragma unroll
      for (int nf = 0; nf < 2; ++nf) {
        int row = wn * 64 + (nq * 2 + nf) * 16 + l15;
#pragma unroll
        for (int ks = 0; ks < 2; ++ks)
          bf[nf][ks] = *(const bf16x8*)&buf[16384 + (row * 8 + ((ks * 4 + hi) ^ ar7)) * 8];
      }
      if (kt + 1 < NKT) stage_half(kt + 1, q);
      asm volatile("s_waitcnt lgkmcnt(8)" ::: "memory");
      __builtin_amdgcn_s_barrier();
      asm volatile("s_waitcnt lgkmcnt(0)" ::: "memory");
      __builtin_amdgcn_sched_barrier(0);
      __builtin_amdgcn_s_setprio(1);
#pragma unroll
      for (int ks = 0; ks < 2; ++ks)
#pragma unroll
        for (int mf = 0; mf < 4; ++mf)
#pragma unroll
          for (int nf = 0; nf < 2; ++nf)
            acc[mq * 4 + mf][nq * 2 + nf] = __builtin_amdgcn_mfma_f32_16x16x32_bf16(
                af[mf][ks], bf[nf][ks], acc[mq * 4 + mf][nq * 2 + nf], 0, 0, 0);
      __builtin_amdgcn_s_setprio(0);
      if (q == 3) asm volatile("s_waitcnt vmcnt(0)" ::: "memory");
      __builtin_amdgcn_s_barrier();
    }
  }

  if (EPI == 3) {
    int chunk = (n0 + wn * 64) >> 6;
#pragma unroll
    for (int mf = 0; mf < 8; ++mf)
#pragma unroll
      for (int j = 0; j < 4; ++j) {
        int row = m0 + wm * 128 + mf * 16 + hi * 4 + j;
        int tv = tgt[row];
        float se = 0.f;
#pragma unroll
        for (int nf = 0; nf < 4; ++nf) {
          int col = n0 + wn * 64 + nf * 16 + l15;
          float v = acc[mf][nf][j] + bias[col];
          se += __expf(v);
          if (col == tv) tlog[row] = v;
        }
        se += __shfl_xor(se, 1);
        se += __shfl_xor(se, 2);
        se += __shfl_xor(se, 4);
        se += __shfl_xor(se, 8);
        if (l15 == 0) partial[(size_t)chunk * M + row] = se;
      }
  } else {  // EPI 4/5: chain-layout XPRE  [t][gid64][b64][cc16][g4]
    constexpr int TTc = (EPI == 4) ? 128 : 64;
#pragma unroll
    for (int mf = 0; mf < 8; ++mf)
#pragma unroll
      for (int nf = 0; nf < 4; ++nf) {
        int col = n0 + wn * 64 + nf * 16 + l15;
        float bv = bias[col];
        int hcol = col & 1023, g = col >> 10;
#pragma unroll
        for (int j = 0; j < 4; ++j) {
          int row = m0 + wm * 128 + mf * 16 + hi * 4 + j;
          int t = row % TTc, b = row / TTc;
          float v = acc[mf][nf][j] + bv;
          Cbf[((((size_t)t * 64 + (hcol >> 4)) * 64 + b) * 16 + (hcol & 15)) * 4 + g] = f2bf(v);
        }
      }
  }
}

// ---------------- persistent LSTM chain kernel (v8, unchanged) ----------------
template <int GRP>
__device__ __forceinline__ void run8(
    int gid, int tid, const unsigned short* __restrict__ Wg,
    const unsigned short* __restrict__ XPC, const float* __restrict__ eb2,
    const float* __restrict__ m0, const unsigned short* __restrict__ ZHX,
    unsigned short* __restrict__ H1X, unsigned short* __restrict__ H2X,
    unsigned short* __restrict__ HDX,
    int* __restrict__ C1, int* __restrict__ C2, int* __restrict__ CD,
    unsigned short* Wl, float* gl) {
  constexpr int COLS = (GRP == 1) ? 8 : 16;
  constexpr int KD   = (GRP == 1) ? 2048 : 1024;
  constexpr int NKS  = KD / 128;
  constexpr int NFR  = (GRP == 1) ? 2 : 4;
  constexpr int NT   = (GRP == 2) ? 63 : 128;
  constexpr int GPR  = KD / 8;
  constexpr int WROWS = 4 * COLS;
  const int lane = tid & 63, w = tid >> 6, l4 = lane >> 4, l15 = lane & 15;
  const int j0 = gid * COLS;

#pragma unroll
  for (int it = 0; it < (WROWS * GPR) / 256; ++it) {
    int L = it * 256 + tid;
    int row = L / GPR;
    int g = (L % GPR) ^ (row & 7);
    int gate = row / COLS, cl = row % COLS;
    gload16(Wg + (size_t)(gate * 1024 + j0 + cl) * KD + g * 8, Wl + (size_t)L * 8);
  }
  const int rr0 = (GRP == 1) ? (tid >> 3) : (tid >> 4);
  const int cc  = (GRP == 1) ? (tid & 7) : (tid & 15);
  const bool cellact = (GRP != 1) || (tid < 128);
  float cst[4];
#pragma unroll
  for (int c = 0; c < 4; ++c) cst[c] = (GRP == 2) ? m0[j0 + cc] : 0.f;
  float br_[4];
  if (GRP == 1) {
#pragma unroll
    for (int g = 0; g < 4; ++g) br_[g] = eb2[g * 1024 + j0 + cc];
  }
  const int kq16 = w * (KD / 32);

  asm volatile("s_waitcnt vmcnt(0)" ::: "memory");
  __syncthreads();

  int2 xq[4];
  if (GRP != 1) {
    const unsigned short* xb = XPC + ((size_t)0 * 64 + gid) * 4096;
#pragma unroll
    for (int c = 0; c < 4; ++c) xq[c] = ldx2(xb + ((c * 16 + rr0) * 16 + cc) * 4);
  }

  for (int t = 0; t < NT; ++t) {
    if (GRP == 0) {
      if (t > 0) wait_all64(C1 + (t - 1) * 64, tid);
    } else if (GRP == 1) {
      wait_all64(C1 + t * 64, tid);
      if (t > 0) wait_all128(C2 + (t - 1) * 128, tid);
    } else {
      if (t > 0) wait_all64(CD + t * 64, tid);
    }
    const unsigned short* slab;
    int jb;
    if (GRP == 0) {
      slab = (t == 0) ? ZHX : H1X + (size_t)(t - 1) * 65536;
      jb = w * 256;
    } else if (GRP == 2) {
      slab = HDX + (size_t)t * 65536;
      jb = w * 256;
    } else {
      if (w < 2) { slab = H1X + (size_t)t * 65536; jb = w * 512; }
      else {
        slab = (t == 0) ? ZHX : H2X + (size_t)(t - 1) * 65536;
        jb = w * 512 - 1024;
      }
    }
    const unsigned short* rp[4];
#pragma unroll
    for (int m = 0; m < 4; ++m)
      rp[m] = slab + (size_t)((jb >> 4) + (l4 >> 1)) * 1024 + (m * 16 + l15) * 16 + (l4 & 1) * 8;
    int4 afr[8][4];
#pragma unroll
    for (int pk = 0; pk < 8; ++pk)
#pragma unroll
      for (int m = 0; m < 4; ++m) afr[pk][m] = ldx4(rp[m] + pk * 2048);
    bf16x8 wb[2][NFR];
#pragma unroll
    for (int n = 0; n < NFR; ++n) {
      int row = n * 16 + l15;
      wb[0][n] = *(const bf16x8*)&Wl[(size_t)row * KD + (size_t)((kq16 + l4) ^ (row & 7)) * 8];
    }
    f32x4 acc[4][NFR] = {};
#pragma unroll
    for (int ks = 0; ks < NKS; ++ks) {
      if (ks + 1 < NKS) {
#pragma unroll
        for (int n = 0; n < NFR; ++n) {
          int row = n * 16 + l15;
          wb[(ks + 1) & 1][n] = *(const bf16x8*)&Wl[(size_t)row * KD +
              (size_t)((kq16 + (ks + 1) * 4 + l4) ^ (row & 7)) * 8];
        }
      }
      vm_wait_c((GRP == 1) ? (ks <= 8 ? 28 : 60 - 4 * ks) : (28 - 4 * ks));
      __builtin_amdgcn_sched_barrier(0);
#pragma unroll
      for (int m = 0; m < 4; ++m)
#pragma unroll
        for (int n = 0; n < NFR; ++n)
          acc[m][n] = __builtin_amdgcn_mfma_f32_16x16x32_bf16(
              *(const bf16x8*)&afr[ks & 7][m], wb[ks & 1][n], acc[m][n], 0, 0, 0);
      if (GRP == 1 && ks < 8) {
#pragma unroll
        for (int m = 0; m < 4; ++m) afr[ks & 7][m] = ldx4(rp[m] + (ks + 8) * 2048);
      }
    }
    unsigned short* outp;
    if (GRP == 0)      outp = H1X + (size_t)t * 65536 + gid * 1024;
    else if (GRP == 2) outp = HDX + (size_t)(t + 1) * 65536 + gid * 1024;
    else               outp = H2X + (size_t)t * 65536 + (size_t)(j0 >> 4) * 1024 + (j0 & 8);
    unsigned short ho[4];
#pragma unroll
    for (int c = 0; c < 4; ++c) {
#pragma unroll
      for (int n = 0; n < NFR; ++n)
#pragma unroll
        for (int j = 0; j < 4; ++j) {
          int ric = l4 * 4 + j;
          int col = n * 16 + l15;
          gl[(w * 16 + ric) * 64 + (col ^ ((ric * 4) & 63))] = acc[c][n][j];
        }
      __syncthreads();
      if (cellact) {
        float G[4];
#pragma unroll
        for (int g = 0; g < 4; ++g) {
          int sw = (g * COLS + cc) ^ ((rr0 * 4) & 63);
          G[g] = gl[(0 * 16 + rr0) * 64 + sw] + gl[(1 * 16 + rr0) * 64 + sw] +
                 gl[(2 * 16 + rr0) * 64 + sw] + gl[(3 * 16 + rr0) * 64 + sw];
        }
        float gi, gf, gg, go;
        if (GRP == 1) {
          gi = G[0] + br_[0]; gf = G[1] + br_[1]; gg = G[2] + br_[2]; go = G[3] + br_[3];
        } else {
          gi = G[0] + bf2f((unsigned short)(xq[c].x & 0xFFFF));
          gf = G[1] + bf2f((unsigned short)((unsigned)xq[c].x >> 16));
          gg = G[2] + bf2f((unsigned short)(xq[c].y & 0xFFFF));
          go = G[3] + bf2f((unsigned short)((unsigned)xq[c].y >> 16));
        }
        float cn = sigm(gf) * cst[c] + sigm(gi) * tanh_f(gg);
        float hn = sigm(go) * tanh_f(cn);
        cst[c] = cn;
        ho[c] = f2bf(hn);
      }
      __syncthreads();
    }
    unsigned short* hb = (unsigned short*)gl;
    if (cellact) {
#pragma unroll
      for (int c = 0; c < 4; ++c) hb[(c * 16 + rr0) * COLS + cc] = ho[c];
    }
    __syncthreads();
    if (GRP != 1) {
      int b2 = tid >> 2, q4 = (tid & 3) * 4;
      ushort4 hv = *(const ushort4*)&hb[b2 * 16 + q4];
      int2 pk;
      pk.x = (int)hv.x | ((int)hv.y << 16);
      pk.y = (int)hv.z | ((int)hv.w << 16);
      stx2u_wt(outp + b2 * 16 + q4, pk);
    } else if (tid < 128) {
      int b2 = tid >> 1, q4 = (tid & 1) * 4;
      ushort4 hv = *(const ushort4*)&hb[b2 * 8 + q4];
      int2 pk;
      pk.x = (int)hv.x | ((int)hv.y << 16);
      pk.y = (int)hv.z | ((int)hv.w << 16);
      stx2u_wt(outp + b2 * 16 + q4, pk);
    }
    if (GRP != 1) {
      int tn = (t + 1 < NT) ? (t + 1) : (NT - 1);
      const unsigned short* xb = XPC + ((size_t)tn * 64 + gid) * 4096;
#pragma unroll
      for (int c = 0; c < 4; ++c) xq[c] = ldx2(xb + ((c * 16 + rr0) * 16 + cc) * 4);
      vm_wait_c(4);
    } else {
      asm volatile("s_waitcnt vmcnt(0)" ::: "memory");
    }
    if (GRP == 0)      post_flag(C1 + t * 64 + gid, tid);
    else if (GRP == 1) post_flag(C2 + t * 128 + gid, tid);
    else               post_flag(CD + (t + 1) * 64 + gid, tid);
  }
}

__global__ __launch_bounds__(256, 1) void chain_kernel(
    const unsigned short* __restrict__ W1T, const unsigned short* __restrict__ W2S,
    const unsigned short* __restrict__ WDT, const unsigned short* __restrict__ XPC1,
    const unsigned short* __restrict__ XPCD, const float* __restrict__ eb2,
    const float* __restrict__ m0, const unsigned short* __restrict__ ZHX,
    unsigned short* __restrict__ H1X, unsigned short* __restrict__ H2X,
    unsigned short* __restrict__ HDX, int* __restrict__ flg) {
  __shared__ unsigned short Wl[65536];
  __shared__ float gl[4 * 16 * 64];
  int bid = blockIdx.x, tid = threadIdx.x;
  int* C1 = flg;
  int* C2 = flg + 8192;
  int* CD = flg + 24576;
  if (bid < 64)
    run8<0>(bid, tid, W1T, XPC1, eb2, nullptr, ZHX, H1X, H2X, HDX, C1, C2, CD, Wl, gl);
  else if (bid < 192)
    run8<1>(bid - 64, tid, W2S, nullptr, eb2, nullptr, ZHX, H1X, H2X, HDX, C1, C2, CD, Wl, gl);
  else
    run8<2>(bid - 192, tid, WDT, XPCD, eb2, m0, ZHX, H1X, H2X, HDX, C1, C2, CD, Wl, gl);
}

// ---------------- batched attention reading block-major slabs directly ----------------
__global__ __launch_bounds__(256) void attn_kernel(const unsigned short* __restrict__ HDX,
                                                   const unsigned short* __restrict__ H2X,
                                                   const int* __restrict__ src_nums,
                                                   unsigned short* __restrict__ cat) {
  __shared__ float hd[Hv];
  __shared__ float sc[Sv];
  __shared__ float al[Sv];
  __shared__ float inv_s;
  int r = blockIdx.x;  // b*T + t
  int b = r >> 6, t = r & 63;
  int tid = threadIdx.x;
#pragma unroll
  for (int i = 0; i < 4; ++i) {
    int j = i * 256 + tid;
    hd[j] = bf2f(HDX[(size_t)t * 65536 + (j >> 4) * 1024 + b * 16 + (j & 15)]);
  }
  __syncthreads();
  int lane = tid & 63, w = tid >> 6;
  {
    int s = w * 32 + (lane >> 1);
    int half = lane & 1;
    const unsigned short* sb = H2X + (size_t)s * 65536 + b * 16;
    const float* hdp = hd + half * 512;
    float ps = 0.f;
#pragma unroll 8
    for (int j = 0; j < 512; j += 2) {
      int e = half * 512 + j;
      unsigned int u = *(const unsigned int*)&sb[(e >> 4) * 1024 + (e & 15)];
      ps += hdp[j] * bf2f((unsigned short)(u & 0xFFFFu));
      ps += hdp[j + 1] * bf2f((unsigned short)(u >> 16));
    }
    ps += __shfl_xor(ps, 1);
    if (half == 0) {
      float v = ps * 0.03125f;  // 1/sqrt(1024)
      if (src_nums[b * Sv + s] == 0) v = -1e30f;
      sc[s] = v;
    }
  }
  __syncthreads();
  if (w == 0) {
    float v0 = sc[lane], v1 = sc[lane + 64];
    float mx = fmaxf(v0, v1);
#pragma unroll
    for (int o = 1; o < 64; o <<= 1) mx = fmaxf(mx, __shfl_xor(mx, o));
    float e0 = __expf(v0 - mx), e1 = __expf(v1 - mx);
    al[lane] = e0;
    al[lane + 64] = e1;
    float ss = e0 + e1;
#pragma unroll
    for (int o = 1; o < 64; o <<= 1) ss += __shfl_xor(ss, o);
    if (lane == 0) inv_s = 1.f / ss;
  }
  __syncthreads();
  float inv = inv_s;
  int j0 = tid * 4;
  int soff = (j0 >> 4) * 1024 + b * 16 + (j0 & 15);
  float a0 = 0, a1 = 0, a2 = 0, a3 = 0;
  for (int s2 = 0; s2 < Sv; ++s2) {
    float a = al[s2];
    ushort4 u = *(const ushort4*)&H2X[(size_t)s2 * 65536 + soff];
    a0 += a * bf2f(u.x);
    a1 += a * bf2f(u.y);
    a2 += a * bf2f(u.z);
    a3 += a * bf2f(u.w);
  }
  ushort4 o4;
  o4.x = f2bf(a0 * inv); o4.y = f2bf(a1 * inv); o4.z = f2bf(a2 * inv); o4.w = f2bf(a3 * inv);
  *(ushort4*)&cat[(size_t)r * 2048 + j0] = o4;
  ushort4 h4;
  h4.x = f2bf(hd[j0]); h4.y = f2bf(hd[j0 + 1]); h4.z = f2bf(hd[j0 + 2]); h4.w = f2bf(hd[j0 + 3]);
  *(ushort4*)&cat[(size_t)r * 2048 + 1024 + j0] = h4;
}

// ---------------- loss ----------------
__global__ __launch_bounds__(256) void loss_row(const float* __restrict__ partial,
                                                const float* __restrict__ tlog,
                                                const int* __restrict__ tgt,
                                                float* __restrict__ rowloss) {
  int r = blockIdx.x * 256 + threadIdx.x;
  float ssum = 0.f;
  for (int c = 0; c < Vv / 64; ++c) ssum += partial[(size_t)c * (Bv * Tv) + r];
  float l = logf(ssum) - tlog[r];
  rowloss[r] = (tgt[r] != 0) ? l : 0.f;
}

__global__ __launch_bounds__(256) void loss_final(const float* __restrict__ rowloss,
                                                  float* __restrict__ out) {
  __shared__ float red[256];
  int tid = threadIdx.x;
  float s = 0.f;
  for (int i = tid; i < Bv * Tv; i += 256) s += rowloss[i];
  red[tid] = s;
  __syncthreads();
  for (int o = 128; o > 0; o >>= 1) {
    if (tid < o) red[tid] += red[tid + o];
    __syncthreads();
  }
  if (tid == 0) out[0] = red[0];
}

extern "C" void kernel_launch(void* const* d_in, const int* in_sizes, int n_in,
                              void* d_out, int out_size, void* d_ws, size_t ws_size,
                              hipStream_t stream) {
  (void)in_sizes; (void)n_in; (void)out_size; (void)ws_size;
  const int* src_nums = (const int*)d_in[0];
  const int* tgt_nums = (const int*)d_in[1];
  const float* src_emb = (const float*)d_in[2];
  const float* tgt_emb = (const float*)d_in[3];
  const float* eWx1 = (const float*)d_in[4];
  const float* eWh1 = (const float*)d_in[5];
  const float* eb1  = (const float*)d_in[6];
  const float* eWx2 = (const float*)d_in[7];
  const float* eWh2 = (const float*)d_in[8];
  const float* eb2  = (const float*)d_in[9];
  const float* dWx  = (const float*)d_in[10];
  const float* dWh  = (const float*)d_in[11];
  const float* db   = (const float*)d_in[12];
  const float* h0   = (const float*)d_in[13];
  const float* m0   = (const float*)d_in[14];
  const float* Wt   = (const float*)d_in[15];
  const float* bt   = (const float*)d_in[16];
  const float* Wo   = (const float*)d_in[17];
  const float* bo   = (const float*)d_in[18];

  char* base = (char*)d_ws;
  size_t off = 0;
  auto alloc = [&](size_t bytes) -> void* {
    void* r = base + off;
    off += (bytes + 255) & ~(size_t)255;
    return r;
  };
  unsigned short* WX1T = (unsigned short*)alloc((size_t)H4v * Hv * 2);
  unsigned short* W1T  = (unsigned short*)alloc((size_t)H4v * Hv * 2);
  unsigned short* W2S  = (unsigned short*)alloc((size_t)H4v * 2048 * 2);
  unsigned short* DWXT = (unsigned short*)alloc((size_t)H4v * Hv * 2);
  unsigned short* WDT  = (unsigned short*)alloc((size_t)H4v * Hv * 2);
  unsigned short* WTT  = (unsigned short*)alloc((size_t)Hv * 2048 * 2);
  unsigned short* WOT  = (unsigned short*)alloc((size_t)Vv * Hv * 2);
  unsigned short* SEMB = (unsigned short*)alloc((size_t)Bv * Sv * Hv * 2);
  unsigned short* TEMB = (unsigned short*)alloc((size_t)Bv * Tv * Hv * 2);
  unsigned short* XPC1 = (unsigned short*)alloc((size_t)Bv * Sv * H4v * 2);
  unsigned short* XPCD = (unsigned short*)alloc((size_t)Bv * Tv * H4v * 2);
  unsigned short* H1X  = (unsigned short*)alloc((size_t)Sv * Bv * Hv * 2);
  unsigned short* H2X  = (unsigned short*)alloc((size_t)Sv * Bv * Hv * 2);
  unsigned short* HDX  = (unsigned short*)alloc((size_t)Tv * Bv * Hv * 2);
  unsigned short* ZHX  = (unsigned short*)alloc((size_t)Bv * Hv * 2);
  unsigned short* CAT  = (unsigned short*)alloc((size_t)Bv * Tv * 2048 * 2);
  unsigned short* ZBUF = (unsigned short*)alloc((size_t)Bv * Tv * Hv * 2);
  float* PART  = (float*)alloc((size_t)(Vv / 64) * (Bv * Tv) * 4);
  float* TLOG  = (float*)alloc((size_t)(Bv * Tv) * 4);
  float* RLOSS = (float*)alloc((size_t)(Bv * Tv) * 4);
  int* FLG     = (int*)alloc(28672 * 4);

  dim3 tb(32, 8);
  transpose_bf16<<<dim3(H4v / 32, Hv / 32), tb, 0, stream>>>(eWx1, WX1T, Hv, H4v, Hv);
  transpose_bf16<<<dim3(H4v / 32, Hv / 32), tb, 0, stream>>>(eWh1, W1T, Hv, H4v, Hv);
  transpose_bf16<<<dim3(H4v / 32, Hv / 32), tb, 0, stream>>>(eWx2, W2S, Hv, H4v, 2048);
  transpose_bf16<<<dim3(H4v / 32, Hv / 32), tb, 0, stream>>>(eWh2, W2S + 1024, Hv, H4v, 2048);
  transpose_bf16<<<dim3(H4v / 32, Hv / 32), tb, 0, stream>>>(dWx, DWXT, Hv, H4v, Hv);
  transpose_bf16<<<dim3(H4v / 32, Hv / 32), tb, 0, stream>>>(dWh, WDT, Hv, H4v, Hv);
  transpose_bf16<<<dim3(Hv / 32, 2048 / 32), tb, 0, stream>>>(Wt, WTT, 2048, Hv, 2048);
  transpose_bf16<<<dim3(Vv / 32, Hv / 32), tb, 0, stream>>>(Wo, WOT, Hv, Vv, Hv);

  init_k<<<256, 256, 0, stream>>>(ZHX, HDX, h0, FLG);
  gather_emb<<<Bv * Sv, 256, 0, stream>>>(src_nums, src_emb, SEMB);
  gather_emb<<<Bv * Tv, 256, 0, stream>>>(tgt_nums, tgt_emb, TEMB);

  // ---- precompute x@Wx (+bias) in chain layout (256^2 phased GEMM) ----
  gemm256<4><<<(Bv * Sv / 256) * (H4v / 256), 512, 0, stream>>>(
      SEMB, WX1T, eb1, XPC1, Bv * Sv, H4v, Hv, Bv * Sv / 256, nullptr, nullptr, nullptr);
  gemm256<5><<<(Bv * Tv / 256) * (H4v / 256), 512, 0, stream>>>(
      TEMB, DWXT, db, XPCD, Bv * Tv, H4v, Hv, Bv * Tv / 256, nullptr, nullptr, nullptr);

  // ---- all recurrent steps in one persistent kernel (flag dataflow) ----
  chain_kernel<<<NBLK, 256, 0, stream>>>(W1T, W2S, WDT, XPC1, XPCD, eb2, m0, ZHX, H1X, H2X,
                                         HDX, FLG);

  // ---- batched attention + concat (slab-direct reads) ----
  attn_kernel<<<Bv * Tv, 256, 0, stream>>>(HDX, H2X, src_nums, CAT);
  // ---- z = tanh(cat @ Wt + bt) ----
  gemm128_tanh<<<dim3(Hv / 128, (Bv * Tv) / 128), 256, 0, stream>>>(
      CAT, WTT, bt, ZBUF, Bv * Tv, Hv, 2048);
  // ---- fused logits GEMM (256^2 phased, XCD-swizzled) ----
  gemm256<3><<<(Bv * Tv / 256) * (Vv / 256), 512, 0, stream>>>(
      ZBUF, WOT, bo, nullptr, Bv * Tv, Vv, Hv, Bv * Tv / 256, PART, TLOG, tgt_nums);
  // ---- loss ----
  loss_row<<<(Bv * Tv) / 256, 256, 0, stream>>>(PART, TLOG, tgt_nums, RLOSS);
  loss_final<<<1, 256, 0, stream>>>(RLOSS, (float*)d_out);
}

// Round 12
// 1688.831 us; speedup vs baseline: 1.1730x; 1.1730x over previous
//
#include <hip/hip_runtime.h>

// Seq2seq LSTM: 2-layer encoder (S=128) + attention decoder (T=64), B=64, H=1024, V=32000.
// v10 = v8 (proven 1820us) + batched attention: 8 decoder timesteps per block (grid 512),
// Henc rows loaded once and reused 8x in registers (score+ctx) -> ~8x less L2/L3 traffic.
// Chain kernel, GEMMs, reshape, loss identical to v8.

#define Bv 64
#define Sv 128
#define Tv 64
#define Hv 1024
#define H4v 4096
#define Vv 32000
#define NBLK 256

using bf16x8 = __attribute__((ext_vector_type(8))) short;
using f32x4  = __attribute__((ext_vector_type(4))) float;

typedef __attribute__((address_space(1))) const void gvoid_t;
typedef __attribute__((address_space(3))) void lvoid_t;

__device__ __forceinline__ void gload16(const void* g, void* l) {
  __builtin_amdgcn_global_load_lds((gvoid_t*)g, (lvoid_t*)l, 16, 0, 0);
}

__device__ __forceinline__ float bf2f(unsigned short u) {
  unsigned int v = ((unsigned int)u) << 16;
  return __uint_as_float(v);
}
__device__ __forceinline__ unsigned short f2bf(float f) {
  unsigned int u = __float_as_uint(f);
  return (unsigned short)((u + 0x7FFFu + ((u >> 16) & 1u)) >> 16);
}
__device__ __forceinline__ float sigm(float x) { return 1.f / (1.f + __expf(-x)); }
__device__ __forceinline__ float tanh_f(float x) {
  float ax = fabsf(x);
  float e = __expf(-2.f * ax);
  float t = (1.f - e) / (1.f + e);
  return copysignf(t, x);
}

// plain cached loads via asm so hand-counted vmcnt stays exact
__device__ __forceinline__ int4 ldx4(const unsigned short* p) {
  int4 r;
  asm volatile("global_load_dwordx4 %0, %1, off" : "=v"(r) : "v"(p));
  return r;
}
__device__ __forceinline__ int2 ldx2(const unsigned short* p) {
  int2 r;
  asm volatile("global_load_dwordx2 %0, %1, off" : "=v"(r) : "v"(p));
  return r;
}
// write-through (coherence point) 8B store for cross-block h exchange
__device__ __forceinline__ void stx2u_wt(unsigned short* p, int2 v) {
  asm volatile("global_store_dwordx2 %0, %1, off sc0 sc1" :: "v"(p), "v"(v) : "memory");
}
// counted waits (literal-folded)
__device__ __forceinline__ void vm_wait_c(int n) {
  switch (n) {
    case 28: asm volatile("s_waitcnt vmcnt(28)" ::: "memory"); break;
    case 24: asm volatile("s_waitcnt vmcnt(24)" ::: "memory"); break;
    case 20: asm volatile("s_waitcnt vmcnt(20)" ::: "memory"); break;
    case 16: asm volatile("s_waitcnt vmcnt(16)" ::: "memory"); break;
    case 12: asm volatile("s_waitcnt vmcnt(12)" ::: "memory"); break;
    case 8:  asm volatile("s_waitcnt vmcnt(8)"  ::: "memory"); break;
    case 4:  asm volatile("s_waitcnt vmcnt(4)"  ::: "memory"); break;
    default: asm volatile("s_waitcnt vmcnt(0)"  ::: "memory"); break;
  }
}

// ---- RMW-free flag sync ----
__device__ __forceinline__ void wait_all64(int* f, int tid) {
  if (tid < 64) {
    int it = 0;
    while (true) {
      int v = __hip_atomic_load(f + tid, __ATOMIC_RELAXED, __HIP_MEMORY_SCOPE_AGENT);
      if (__all(v != 0)) break;
      __builtin_amdgcn_s_sleep(2);
      if (++it > (1 << 17)) break;  // bounded: fail loud, never hang
    }
  }
  __syncthreads();
}
__device__ __forceinline__ void wait_all128(int* f, int tid) {
  if (tid < 64) {
    int it = 0;
    while (true) {
      int a = __hip_atomic_load(f + tid, __ATOMIC_RELAXED, __HIP_MEMORY_SCOPE_AGENT);
      int b = __hip_atomic_load(f + tid + 64, __ATOMIC_RELAXED, __HIP_MEMORY_SCOPE_AGENT);
      if (__all((a != 0) && (b != 0))) break;
      __builtin_amdgcn_s_sleep(2);
      if (++it > (1 << 17)) break;
    }
  }
  __syncthreads();
}
__device__ __forceinline__ void post_flag(int* f, int tid) {
  __syncthreads();  // all waves drained their h stores before this
  if (tid == 0) __hip_atomic_store(f, 1, __ATOMIC_RELAXED, __HIP_MEMORY_SCOPE_AGENT);
}

// ---------------- transpose + fp32->bf16 convert: out[c][r] (row length ostride) ----------------
__global__ __launch_bounds__(256) void transpose_bf16(const float* __restrict__ in,
                                                      unsigned short* __restrict__ out,
                                                      int R, int C, int ostride) {
  __shared__ float tile[32][33];
  int tx = threadIdx.x, ty = threadIdx.y;
  int c0 = blockIdx.x * 32, r0 = blockIdx.y * 32;
#pragma unroll
  for (int i = 0; i < 32; i += 8)
    tile[ty + i][tx] = in[(size_t)(r0 + ty + i) * C + c0 + tx];
  __syncthreads();
#pragma unroll
  for (int i = 0; i < 32; i += 8)
    out[(size_t)(c0 + ty + i) * ostride + r0 + tx] = f2bf(tile[tx][ty + i]);
}

// ---------------- embedding gather (fp32 table -> bf16 rows) ----------------
__global__ __launch_bounds__(256) void gather_emb(const int* __restrict__ toks,
                                                  const float* __restrict__ emb,
                                                  unsigned short* __restrict__ dst) {
  int r = blockIdx.x, tid = threadIdx.x;
  int tok = toks[r];
  int j = tid * 4;
  float4 v = *(const float4*)&emb[(size_t)tok * Hv + j];
  ushort4 o;
  o.x = f2bf(v.x); o.y = f2bf(v.y); o.z = f2bf(v.z); o.w = f2bf(v.w);
  *(ushort4*)&dst[(size_t)r * Hv + j] = o;
}

// ---------------- init: zero slab, HDX slab 0 = h0 broadcast (block-major), flags ----------------
__global__ __launch_bounds__(256) void init_k(unsigned short* __restrict__ zhx,
                                              unsigned short* __restrict__ hdx0,
                                              const float* __restrict__ h0,
                                              int* __restrict__ flg) {
  int idx = blockIdx.x * 256 + threadIdx.x;  // 65536 = 64*1024
  int j = idx & (Hv - 1);
  int b = idx >> 10;
  zhx[idx] = 0;
  hdx0[(j >> 4) * 1024 + b * 16 + (j & 15)] = f2bf(h0[j]);
  if (idx < 28672) flg[idx] = 0;
}

// ---------------- generic 128x128 MFMA GEMM, B pre-transposed [N][K] bf16 ----------------
// EPI: 2 = tanh -> bf16 (+bias), 3 = fused logits (exp-sum partials + tgt gather, m-fastest grid),
//      4/5 = chain-layout XPRE write (+bias), TT = 128 / 64.
template <int EPI>
__global__ __launch_bounds__(256) void gemm128(const unsigned short* __restrict__ A,
                                               const unsigned short* __restrict__ Bt,
                                               const float* __restrict__ bias,
                                               unsigned short* __restrict__ Cbf,
                                               int M, int N, int K,
                                               float* __restrict__ partial,
                                               float* __restrict__ tlog,
                                               const int* __restrict__ tgt) {
  __shared__ unsigned short As[128 * 64];
  __shared__ unsigned short Bs[128 * 64];
  int tid = threadIdx.x, lane = tid & 63, w = tid >> 6;
  int wr = w >> 1, wc = w & 1;
  int m0 = (EPI == 3) ? blockIdx.x * 128 : blockIdx.y * 128;
  int n0 = (EPI == 3) ? blockIdx.y * 128 : blockIdx.x * 128;
  f32x4 acc[4][4] = {};
  for (int k0 = 0; k0 < K; k0 += 64) {
    __syncthreads();
#pragma unroll
    for (int q = 0; q < 4; ++q) {
      int idx = q * 256 + tid;
      int row = idx >> 3, phys = idx & 7, lg = phys ^ (row & 7);
      gload16(A + (size_t)(m0 + row) * K + k0 + lg * 8, &As[idx * 8]);
    }
#pragma unroll
    for (int q = 0; q < 4; ++q) {
      int idx = q * 256 + tid;
      int row = idx >> 3, phys = idx & 7, lg = phys ^ (row & 7);
      gload16(Bt + (size_t)(n0 + row) * K + k0 + lg * 8, &Bs[idx * 8]);
    }
    __syncthreads();
#pragma unroll
    for (int kk = 0; kk < 64; kk += 32) {
      int lgb = (kk >> 3) + (lane >> 4);
      bf16x8 af[4], bfr[4];
#pragma unroll
      for (int m = 0; m < 4; ++m) {
        int row = wr * 64 + m * 16 + (lane & 15);
        af[m] = *(const bf16x8*)&As[(row * 8 + (lgb ^ (row & 7))) * 8];
      }
#pragma unroll
      for (int n = 0; n < 4; ++n) {
        int row = wc * 64 + n * 16 + (lane & 15);
        bfr[n] = *(const bf16x8*)&Bs[(row * 8 + (lgb ^ (row & 7))) * 8];
      }
#pragma unroll
      for (int m = 0; m < 4; ++m)
#pragma unroll
        for (int n = 0; n < 4; ++n)
          acc[m][n] = __builtin_amdgcn_mfma_f32_16x16x32_bf16(af[m], bfr[n], acc[m][n], 0, 0, 0);
    }
  }
  if (EPI == 2) {
#pragma unroll
    for (int m = 0; m < 4; ++m)
#pragma unroll
      for (int n = 0; n < 4; ++n) {
        int col = n0 + wc * 64 + n * 16 + (lane & 15);
        float bv = bias[col];
#pragma unroll
        for (int j = 0; j < 4; ++j) {
          int row = m0 + wr * 64 + m * 16 + (lane >> 4) * 4 + j;
          float v = acc[m][n][j] + bv;
          Cbf[(size_t)row * N + col] = f2bf(tanhf(v));
        }
      }
  } else if (EPI == 3) {
    int chunk = (n0 + wc * 64) >> 6;  // 64-col chunk owned by this wave
#pragma unroll
    for (int m = 0; m < 4; ++m)
#pragma unroll
      for (int j = 0; j < 4; ++j) {
        int row = m0 + wr * 64 + m * 16 + (lane >> 4) * 4 + j;
        int tv = tgt[row];
        float se = 0.f;
#pragma unroll
        for (int n = 0; n < 4; ++n) {
          int col = n0 + wc * 64 + n * 16 + (lane & 15);
          float v = acc[m][n][j] + bias[col];
          se += __expf(v);  // logits are O(1): no max-subtraction needed
          if (col == tv) tlog[row] = v;
        }
        se += __shfl_xor(se, 1);
        se += __shfl_xor(se, 2);
        se += __shfl_xor(se, 4);
        se += __shfl_xor(se, 8);
        if ((lane & 15) == 0) partial[(size_t)chunk * M + row] = se;
      }
  } else {  // EPI 4/5: chain-layout XPRE  [t][gid64][b64][cc16][g4]
    constexpr int TTc = (EPI == 4) ? 128 : 64;
#pragma unroll
    for (int m = 0; m < 4; ++m)
#pragma unroll
      for (int n = 0; n < 4; ++n) {
        int col = n0 + wc * 64 + n * 16 + (lane & 15);
        float bv = bias[col];
        int hcol = col & 1023, g = col >> 10;
#pragma unroll
        for (int j = 0; j < 4; ++j) {
          int row = m0 + wr * 64 + m * 16 + (lane >> 4) * 4 + j;
          int t = row % TTc, b = row / TTc;
          float v = acc[m][n][j] + bv;
          Cbf[((((size_t)t * 64 + (hcol >> 4)) * 64 + b) * 16 + (hcol & 15)) * 4 + g] = f2bf(v);
        }
      }
  }
}

// ---------------- persistent LSTM chain kernel (v8, unchanged) ----------------
template <int GRP>
__device__ __forceinline__ void run8(
    int gid, int tid, const unsigned short* __restrict__ Wg,
    const unsigned short* __restrict__ XPC, const float* __restrict__ eb2,
    const float* __restrict__ m0, const unsigned short* __restrict__ ZHX,
    unsigned short* __restrict__ H1X, unsigned short* __restrict__ H2X,
    unsigned short* __restrict__ HDX,
    int* __restrict__ C1, int* __restrict__ C2, int* __restrict__ CD,
    unsigned short* Wl, float* gl) {
  constexpr int COLS = (GRP == 1) ? 8 : 16;
  constexpr int KD   = (GRP == 1) ? 2048 : 1024;
  constexpr int NKS  = KD / 128;
  constexpr int NFR  = (GRP == 1) ? 2 : 4;
  constexpr int NT   = (GRP == 2) ? 63 : 128;
  constexpr int GPR  = KD / 8;
  constexpr int WROWS = 4 * COLS;
  const int lane = tid & 63, w = tid >> 6, l4 = lane >> 4, l15 = lane & 15;
  const int j0 = gid * COLS;

#pragma unroll
  for (int it = 0; it < (WROWS * GPR) / 256; ++it) {
    int L = it * 256 + tid;
    int row = L / GPR;
    int g = (L % GPR) ^ (row & 7);
    int gate = row / COLS, cl = row % COLS;
    gload16(Wg + (size_t)(gate * 1024 + j0 + cl) * KD + g * 8, Wl + (size_t)L * 8);
  }
  const int rr0 = (GRP == 1) ? (tid >> 3) : (tid >> 4);
  const int cc  = (GRP == 1) ? (tid & 7) : (tid & 15);
  const bool cellact = (GRP != 1) || (tid < 128);
  float cst[4];
#pragma unroll
  for (int c = 0; c < 4; ++c) cst[c] = (GRP == 2) ? m0[j0 + cc] : 0.f;
  float br_[4];
  if (GRP == 1) {
#pragma unroll
    for (int g = 0; g < 4; ++g) br_[g] = eb2[g * 1024 + j0 + cc];
  }
  const int kq16 = w * (KD / 32);

  asm volatile("s_waitcnt vmcnt(0)" ::: "memory");
  __syncthreads();

  int2 xq[4];
  if (GRP != 1) {
    const unsigned short* xb = XPC + ((size_t)0 * 64 + gid) * 4096;
#pragma unroll
    for (int c = 0; c < 4; ++c) xq[c] = ldx2(xb + ((c * 16 + rr0) * 16 + cc) * 4);
  }

  for (int t = 0; t < NT; ++t) {
    if (GRP == 0) {
      if (t > 0) wait_all64(C1 + (t - 1) * 64, tid);
    } else if (GRP == 1) {
      wait_all64(C1 + t * 64, tid);
      if (t > 0) wait_all128(C2 + (t - 1) * 128, tid);
    } else {
      if (t > 0) wait_all64(CD + t * 64, tid);
    }
    const unsigned short* slab;
    int jb;
    if (GRP == 0) {
      slab = (t == 0) ? ZHX : H1X + (size_t)(t - 1) * 65536;
      jb = w * 256;
    } else if (GRP == 2) {
      slab = HDX + (size_t)t * 65536;
      jb = w * 256;
    } else {
      if (w < 2) { slab = H1X + (size_t)t * 65536; jb = w * 512; }
      else {
        slab = (t == 0) ? ZHX : H2X + (size_t)(t - 1) * 65536;
        jb = w * 512 - 1024;
      }
    }
    const unsigned short* rp[4];
#pragma unroll
    for (int m = 0; m < 4; ++m)
      rp[m] = slab + (size_t)((jb >> 4) + (l4 >> 1)) * 1024 + (m * 16 + l15) * 16 + (l4 & 1) * 8;
    int4 afr[8][4];
#pragma unroll
    for (int pk = 0; pk < 8; ++pk)
#pragma unroll
      for (int m = 0; m < 4; ++m) afr[pk][m] = ldx4(rp[m] + pk * 2048);
    bf16x8 wb[2][NFR];
#pragma unroll
    for (int n = 0; n < NFR; ++n) {
      int row = n * 16 + l15;
      wb[0][n] = *(const bf16x8*)&Wl[(size_t)row * KD + (size_t)((kq16 + l4) ^ (row & 7)) * 8];
    }
    f32x4 acc[4][NFR] = {};
#pragma unroll
    for (int ks = 0; ks < NKS; ++ks) {
      if (ks + 1 < NKS) {
#pragma unroll
        for (int n = 0; n < NFR; ++n) {
          int row = n * 16 + l15;
          wb[(ks + 1) & 1][n] = *(const bf16x8*)&Wl[(size_t)row * KD +
              (size_t)((kq16 + (ks + 1) * 4 + l4) ^ (row & 7)) * 8];
        }
      }
      vm_wait_c((GRP == 1) ? (ks <= 8 ? 28 : 60 - 4 * ks) : (28 - 4 * ks));
      __builtin_amdgcn_sched_barrier(0);
#pragma unroll
      for (int m = 0; m < 4; ++m)
#pragma unroll
        for (int n = 0; n < NFR; ++n)
          acc[m][n] = __builtin_amdgcn_mfma_f32_16x16x32_bf16(
              *(const bf16x8*)&afr[ks & 7][m], wb[ks & 1][n], acc[m][n], 0, 0, 0);
      if (GRP == 1 && ks < 8) {
#pragma unroll
        for (int m = 0; m < 4; ++m) afr[ks & 7][m] = ldx4(rp[m] + (ks + 8) * 2048);
      }
    }
    unsigned short* outp;
    if (GRP == 0)      outp = H1X + (size_t)t * 65536 + gid * 1024;
    else if (GRP == 2) outp = HDX + (size_t)(t + 1) * 65536 + gid * 1024;
    else               outp = H2X + (size_t)t * 65536 + (size_t)(j0 >> 4) * 1024 + (j0 & 8);
    unsigned short ho[4];
#pragma unroll
    for (int c = 0; c < 4; ++c) {
#pragma unroll
      for (int n = 0; n < NFR; ++n)
#pragma unroll
        for (int j = 0; j < 4; ++j) {
          int ric = l4 * 4 + j;
          int col = n * 16 + l15;
          gl[(w * 16 + ric) * 64 + (col ^ ((ric * 4) & 63))] = acc[c][n][j];
        }
      __syncthreads();
      if (cellact) {
        float G[4];
#pragma unroll
        for (int g = 0; g < 4; ++g) {
          int sw = (g * COLS + cc) ^ ((rr0 * 4) & 63);
          G[g] = gl[(0 * 16 + rr0) * 64 + sw] + gl[(1 * 16 + rr0) * 64 + sw] +
                 gl[(2 * 16 + rr0) * 64 + sw] + gl[(3 * 16 + rr0) * 64 + sw];
        }
        float gi, gf, gg, go;
        if (GRP == 1) {
          gi = G[0] + br_[0]; gf = G[1] + br_[1]; gg = G[2] + br_[2]; go = G[3] + br_[3];
        } else {
          gi = G[0] + bf2f((unsigned short)(xq[c].x & 0xFFFF));
          gf = G[1] + bf2f((unsigned short)((unsigned)xq[c].x >> 16));
          gg = G[2] + bf2f((unsigned short)(xq[c].y & 0xFFFF));
          go = G[3] + bf2f((unsigned short)((unsigned)xq[c].y >> 16));
        }
        float cn = sigm(gf) * cst[c] + sigm(gi) * tanh_f(gg);
        float hn = sigm(go) * tanh_f(cn);
        cst[c] = cn;
        ho[c] = f2bf(hn);
      }
      __syncthreads();
    }
    unsigned short* hb = (unsigned short*)gl;
    if (cellact) {
#pragma unroll
      for (int c = 0; c < 4; ++c) hb[(c * 16 + rr0) * COLS + cc] = ho[c];
    }
    __syncthreads();
    if (GRP != 1) {
      int b2 = tid >> 2, q4 = (tid & 3) * 4;
      ushort4 hv = *(const ushort4*)&hb[b2 * 16 + q4];
      int2 pk;
      pk.x = (int)hv.x | ((int)hv.y << 16);
      pk.y = (int)hv.z | ((int)hv.w << 16);
      stx2u_wt(outp + b2 * 16 + q4, pk);
    } else if (tid < 128) {
      int b2 = tid >> 1, q4 = (tid & 1) * 4;
      ushort4 hv = *(const ushort4*)&hb[b2 * 8 + q4];
      int2 pk;
      pk.x = (int)hv.x | ((int)hv.y << 16);
      pk.y = (int)hv.z | ((int)hv.w << 16);
      stx2u_wt(outp + b2 * 16 + q4, pk);
    }
    if (GRP != 1) {
      int tn = (t + 1 < NT) ? (t + 1) : (NT - 1);
      const unsigned short* xb = XPC + ((size_t)tn * 64 + gid) * 4096;
#pragma unroll
      for (int c = 0; c < 4; ++c) xq[c] = ldx2(xb + ((c * 16 + rr0) * 16 + cc) * 4);
      vm_wait_c(4);
    } else {
      asm volatile("s_waitcnt vmcnt(0)" ::: "memory");
    }
    if (GRP == 0)      post_flag(C1 + t * 64 + gid, tid);
    else if (GRP == 1) post_flag(C2 + t * 128 + gid, tid);
    else               post_flag(CD + (t + 1) * 64 + gid, tid);
  }
}

__global__ __launch_bounds__(256, 1) void chain_kernel(
    const unsigned short* __restrict__ W1T, const unsigned short* __restrict__ W2S,
    const unsigned short* __restrict__ WDT, const unsigned short* __restrict__ XPC1,
    const unsigned short* __restrict__ XPCD, const float* __restrict__ eb2,
    const float* __restrict__ m0, const unsigned short* __restrict__ ZHX,
    unsigned short* __restrict__ H1X, unsigned short* __restrict__ H2X,
    unsigned short* __restrict__ HDX, int* __restrict__ flg) {
  __shared__ unsigned short Wl[65536];
  __shared__ float gl[4 * 16 * 64];
  int bid = blockIdx.x, tid = threadIdx.x;
  int* C1 = flg;
  int* C2 = flg + 8192;
  int* CD = flg + 24576;
  if (bid < 64)
    run8<0>(bid, tid, W1T, XPC1, eb2, nullptr, ZHX, H1X, H2X, HDX, C1, C2, CD, Wl, gl);
  else if (bid < 192)
    run8<1>(bid - 64, tid, W2S, nullptr, eb2, nullptr, ZHX, H1X, H2X, HDX, C1, C2, CD, Wl, gl);
  else
    run8<2>(bid - 192, tid, WDT, XPCD, eb2, m0, ZHX, H1X, H2X, HDX, C1, C2, CD, Wl, gl);
}

// ---------------- reshape block-major slabs -> row-major HENC/HDEC ----------------
__global__ __launch_bounds__(256) void reshape_h(const unsigned short* __restrict__ H2X,
                                                 const unsigned short* __restrict__ HDX,
                                                 unsigned short* __restrict__ HENC,
                                                 unsigned short* __restrict__ HDEC) {
  int row = blockIdx.x, tid = threadIdx.x;
  int g = tid >> 2, c = (tid & 3) * 4;
  if (row < Bv * Sv) {
    int b = row >> 7, s = row & 127;
    ushort4 v = *(const ushort4*)&H2X[(size_t)s * 65536 + g * 1024 + b * 16 + c];
    *(ushort4*)&HENC[(size_t)row * Hv + tid * 4] = v;
  } else {
    int r2 = row - Bv * Sv;
    int b = r2 >> 6, t = r2 & 63;
    ushort4 v = *(const ushort4*)&HDX[(size_t)t * 65536 + g * 1024 + b * 16 + c];
    *(ushort4*)&HDEC[(size_t)r2 * Hv + tid * 4] = v;
  }
}

// ---------------- batched attention: 8 decoder steps per block ----------------
__global__ __launch_bounds__(256) void attn_kernel(const unsigned short* __restrict__ Hdec,
                                                   const unsigned short* __restrict__ Henc,
                                                   const int* __restrict__ src_nums,
                                                   unsigned short* __restrict__ cat) {
  __shared__ float hd[8][Hv];   // 32 KB
  __shared__ float sc[8][Sv];   // 4 KB
  __shared__ float al[8][Sv];   // 4 KB
  __shared__ float inv_s[8];
  int b = blockIdx.x >> 3;
  int tg = (blockIdx.x & 7) * 8;  // first t of this 8-step group
  int tid = threadIdx.x;
#pragma unroll
  for (int tt = 0; tt < 8; ++tt)
#pragma unroll
    for (int i = 0; i < 4; ++i) {
      int j = i * 256 + tid;
      hd[tt][j] = bf2f(Hdec[((size_t)(b * Tv + tg + tt)) * Hv + j]);
    }
  __syncthreads();
  int lane = tid & 63, w = tid >> 6;
  {
    int s = w * 32 + (lane >> 1);
    int half = lane & 1;
    const unsigned short* hrow = Henc + ((size_t)(b * Sv + s)) * Hv + half * 512;
    float ps[8] = {};
#pragma unroll 4
    for (int j = 0; j < 512; j += 2) {
      unsigned int u = *(const unsigned int*)&hrow[j];
      float e0 = bf2f((unsigned short)(u & 0xFFFFu));
      float e1 = bf2f((unsigned short)(u >> 16));
      int jj = half * 512 + j;
#pragma unroll
      for (int tt = 0; tt < 8; ++tt)
        ps[tt] += hd[tt][jj] * e0 + hd[tt][jj + 1] * e1;
    }
    bool masked = (src_nums[b * Sv + s] == 0);
#pragma unroll
    for (int tt = 0; tt < 8; ++tt) {
      float p = ps[tt] + __shfl_xor(ps[tt], 1);
      if (half == 0) sc[tt][s] = masked ? -1e30f : (p * 0.03125f);  // 1/sqrt(1024)
    }
  }
  __syncthreads();
  // softmax: wave w handles tt = 2w, 2w+1
#pragma unroll
  for (int k = 0; k < 2; ++k) {
    int tt = w * 2 + k;
    float v0 = sc[tt][lane], v1 = sc[tt][lane + 64];
    float mx = fmaxf(v0, v1);
#pragma unroll
    for (int o = 1; o < 64; o <<= 1) mx = fmaxf(mx, __shfl_xor(mx, o));
    float e0 = __expf(v0 - mx), e1 = __expf(v1 - mx);
    al[tt][lane] = e0;
    al[tt][lane + 64] = e1;
    float ss = e0 + e1;
#pragma unroll
    for (int o = 1; o < 64; o <<= 1) ss += __shfl_xor(ss, o);
    if (lane == 0) inv_s[tt] = 1.f / ss;
  }
  __syncthreads();
  int j0 = tid * 4;
  float a[8][4] = {};
  for (int s2 = 0; s2 < Sv; ++s2) {
    ushort4 u = *(const ushort4*)&Henc[((size_t)(b * Sv + s2)) * Hv + j0];
    float e0 = bf2f(u.x), e1 = bf2f(u.y), e2 = bf2f(u.z), e3 = bf2f(u.w);
#pragma unroll
    for (int tt = 0; tt < 8; ++tt) {
      float av = al[tt][s2];
      a[tt][0] += av * e0;
      a[tt][1] += av * e1;
      a[tt][2] += av * e2;
      a[tt][3] += av * e3;
    }
  }
#pragma unroll
  for (int tt = 0; tt < 8; ++tt) {
    size_t r = (size_t)b * Tv + tg + tt;
    float inv = inv_s[tt];
    ushort4 o4;
    o4.x = f2bf(a[tt][0] * inv); o4.y = f2bf(a[tt][1] * inv);
    o4.z = f2bf(a[tt][2] * inv); o4.w = f2bf(a[tt][3] * inv);
    *(ushort4*)&cat[r * 2048 + j0] = o4;
    ushort4 h4;
    h4.x = f2bf(hd[tt][j0]);     h4.y = f2bf(hd[tt][j0 + 1]);
    h4.z = f2bf(hd[tt][j0 + 2]); h4.w = f2bf(hd[tt][j0 + 3]);
    *(ushort4*)&cat[r * 2048 + 1024 + j0] = h4;
  }
}

// ---------------- loss: per-row lse - tgt_logit, then deterministic sum ----------------
__global__ __launch_bounds__(256) void loss_row(const float* __restrict__ partial,
                                                const float* __restrict__ tlog,
                                                const int* __restrict__ tgt,
                                                float* __restrict__ rowloss) {
  int r = blockIdx.x * 256 + threadIdx.x;
  float ssum = 0.f;
  for (int c = 0; c < Vv / 64; ++c) ssum += partial[(size_t)c * (Bv * Tv) + r];
  float l = logf(ssum) - tlog[r];
  rowloss[r] = (tgt[r] != 0) ? l : 0.f;
}

__global__ __launch_bounds__(256) void loss_final(const float* __restrict__ rowloss,
                                                  float* __restrict__ out) {
  __shared__ float red[256];
  int tid = threadIdx.x;
  float s = 0.f;
  for (int i = tid; i < Bv * Tv; i += 256) s += rowloss[i];
  red[tid] = s;
  __syncthreads();
  for (int o = 128; o > 0; o >>= 1) {
    if (tid < o) red[tid] += red[tid + o];
    __syncthreads();
  }
  if (tid == 0) out[0] = red[0];
}

extern "C" void kernel_launch(void* const* d_in, const int* in_sizes, int n_in,
                              void* d_out, int out_size, void* d_ws, size_t ws_size,
                              hipStream_t stream) {
  (void)in_sizes; (void)n_in; (void)out_size; (void)ws_size;
  const int* src_nums = (const int*)d_in[0];
  const int* tgt_nums = (const int*)d_in[1];
  const float* src_emb = (const float*)d_in[2];
  const float* tgt_emb = (const float*)d_in[3];
  const float* eWx1 = (const float*)d_in[4];
  const float* eWh1 = (const float*)d_in[5];
  const float* eb1  = (const float*)d_in[6];
  const float* eWx2 = (const float*)d_in[7];
  const float* eWh2 = (const float*)d_in[8];
  const float* eb2  = (const float*)d_in[9];
  const float* dWx  = (const float*)d_in[10];
  const float* dWh  = (const float*)d_in[11];
  const float* db   = (const float*)d_in[12];
  const float* h0   = (const float*)d_in[13];
  const float* m0   = (const float*)d_in[14];
  const float* Wt   = (const float*)d_in[15];
  const float* bt   = (const float*)d_in[16];
  const float* Wo   = (const float*)d_in[17];
  const float* bo   = (const float*)d_in[18];

  char* base = (char*)d_ws;
  size_t off = 0;
  auto alloc = [&](size_t bytes) -> void* {
    void* r = base + off;
    off += (bytes + 255) & ~(size_t)255;
    return r;
  };
  unsigned short* WX1T = (unsigned short*)alloc((size_t)H4v * Hv * 2);
  unsigned short* W1T  = (unsigned short*)alloc((size_t)H4v * Hv * 2);
  unsigned short* W2S  = (unsigned short*)alloc((size_t)H4v * 2048 * 2);
  unsigned short* DWXT = (unsigned short*)alloc((size_t)H4v * Hv * 2);
  unsigned short* WDT  = (unsigned short*)alloc((size_t)H4v * Hv * 2);
  unsigned short* WTT  = (unsigned short*)alloc((size_t)Hv * 2048 * 2);
  unsigned short* WOT  = (unsigned short*)alloc((size_t)Vv * Hv * 2);
  unsigned short* SEMB = (unsigned short*)alloc((size_t)Bv * Sv * Hv * 2);
  unsigned short* TEMB = (unsigned short*)alloc((size_t)Bv * Tv * Hv * 2);
  unsigned short* XPC1 = (unsigned short*)alloc((size_t)Bv * Sv * H4v * 2);
  unsigned short* XPCD = (unsigned short*)alloc((size_t)Bv * Tv * H4v * 2);
  unsigned short* HENC = (unsigned short*)alloc((size_t)Bv * Sv * Hv * 2);
  unsigned short* HDEC = (unsigned short*)alloc((size_t)Bv * Tv * Hv * 2);
  unsigned short* H1X  = (unsigned short*)alloc((size_t)Sv * Bv * Hv * 2);
  unsigned short* H2X  = (unsigned short*)alloc((size_t)Sv * Bv * Hv * 2);
  unsigned short* HDX  = (unsigned short*)alloc((size_t)Tv * Bv * Hv * 2);
  unsigned short* ZHX  = (unsigned short*)alloc((size_t)Bv * Hv * 2);
  unsigned short* CAT  = (unsigned short*)alloc((size_t)Bv * Tv * 2048 * 2);
  unsigned short* ZBUF = (unsigned short*)alloc((size_t)Bv * Tv * Hv * 2);
  float* PART  = (float*)alloc((size_t)(Vv / 64) * (Bv * Tv) * 4);
  float* TLOG  = (float*)alloc((size_t)(Bv * Tv) * 4);
  float* RLOSS = (float*)alloc((size_t)(Bv * Tv) * 4);
  int* FLG     = (int*)alloc(28672 * 4);

  dim3 tb(32, 8);
  transpose_bf16<<<dim3(H4v / 32, Hv / 32), tb, 0, stream>>>(eWx1, WX1T, Hv, H4v, Hv);
  transpose_bf16<<<dim3(H4v / 32, Hv / 32), tb, 0, stream>>>(eWh1, W1T, Hv, H4v, Hv);
  transpose_bf16<<<dim3(H4v / 32, Hv / 32), tb, 0, stream>>>(eWx2, W2S, Hv, H4v, 2048);
  transpose_bf16<<<dim3(H4v / 32, Hv / 32), tb, 0, stream>>>(eWh2, W2S + 1024, Hv, H4v, 2048);
  transpose_bf16<<<dim3(H4v / 32, Hv / 32), tb, 0, stream>>>(dWx, DWXT, Hv, H4v, Hv);
  transpose_bf16<<<dim3(H4v / 32, Hv / 32), tb, 0, stream>>>(dWh, WDT, Hv, H4v, Hv);
  transpose_bf16<<<dim3(Hv / 32, 2048 / 32), tb, 0, stream>>>(Wt, WTT, 2048, Hv, 2048);
  transpose_bf16<<<dim3(Vv / 32, Hv / 32), tb, 0, stream>>>(Wo, WOT, Hv, Vv, Hv);

  init_k<<<256, 256, 0, stream>>>(ZHX, HDX, h0, FLG);
  gather_emb<<<Bv * Sv, 256, 0, stream>>>(src_nums, src_emb, SEMB);
  gather_emb<<<Bv * Tv, 256, 0, stream>>>(tgt_nums, tgt_emb, TEMB);

  // ---- precompute x@Wx (+bias) in chain layout ----
  gemm128<4><<<dim3(H4v / 128, (Bv * Sv) / 128), 256, 0, stream>>>(
      SEMB, WX1T, eb1, XPC1, Bv * Sv, H4v, Hv, nullptr, nullptr, nullptr);
  gemm128<5><<<dim3(H4v / 128, (Bv * Tv) / 128), 256, 0, stream>>>(
      TEMB, DWXT, db, XPCD, Bv * Tv, H4v, Hv, nullptr, nullptr, nullptr);

  // ---- all recurrent steps in one persistent kernel (flag dataflow) ----
  chain_kernel<<<NBLK, 256, 0, stream>>>(W1T, W2S, WDT, XPC1, XPCD, eb2, m0, ZHX, H1X, H2X,
                                         HDX, FLG);

  // ---- slabs -> row-major HENC/HDEC ----
  reshape_h<<<Bv * Sv + Bv * Tv, 256, 0, stream>>>(H2X, HDX, HENC, HDEC);

  // ---- batched attention + concat (8 t per block) ----
  attn_kernel<<<Bv * 8, 256, 0, stream>>>(HDEC, HENC, src_nums, CAT);
  // ---- z = tanh(cat @ Wt + bt) ----
  gemm128<2><<<dim3(Hv / 128, (Bv * Tv) / 128), 256, 0, stream>>>(
      CAT, WTT, bt, ZBUF, Bv * Tv, Hv, 2048, nullptr, nullptr, nullptr);
  // ---- fused logits GEMM (m-fastest grid for WOT reuse) ----
  gemm128<3><<<dim3((Bv * Tv) / 128, Vv / 128), 256, 0, stream>>>(
      ZBUF, WOT, bo, nullptr, Bv * Tv, Vv, Hv, PART, TLOG, tgt_nums);
  // ---- loss ----
  loss_row<<<(Bv * Tv) / 256, 256, 0, stream>>>(PART, TLOG, tgt_nums, RLOSS);
  loss_final<<<1, 256, 0, stream>>>(RLOSS, (float*)d_out);
}